// Round 6
// baseline (1281.042 us; speedup 1.0000x reference)
//
#include <hip/hip_runtime.h>
#include <math.h>

// Problem constants
#define BB 32
#define PP 2048
#define DD 768
#define TT 3
#define OO 128
#define HH 192
#define CC 32              // chunks of P per batch for the streaming phase
#define ROWS (PP / CC)     // 64 rows per chunk
#define VC 1024            // fixed virtual chunks for main phase (determinism)
#define SCALE 0.03608439182435161f  // 1/sqrt(768)
#define GELU_C 0.70710678118654752f

struct Params {
    const float* x; const int* mask; const float* tt;
    const float* Wq; const float* bq; const float* Wk;
    const float* Wv; const float* bv; const float* Wo; const float* bo;
    const float* h1w; const float* h1b; const float* h2w; const float* h2b;
    float* out;
    unsigned* bar;     // [0..255] 16 padded counters (stride 16), [256] release
    float* q; float* kq; float* xap; float* lp; float* xa;
    float* partV; float* partO; float* partH;
};

// ---------------------------------------------------------------------------
// Grid barrier (regular launch; grid sized to guaranteed co-residency).
// 16 padded arrival counters; block 0 sums (ACQUIRE) and publishes release.
// Bounded spin: if co-residency ever fails we produce a fast wrong answer
// (absmax signal) instead of a hang.
// ---------------------------------------------------------------------------
__device__ inline void gbar(unsigned* cnt, unsigned* rel, int phase) {
    __syncthreads();
    if (threadIdx.x == 0) {
        __hip_atomic_fetch_add(&cnt[(blockIdx.x & 15) * 16], 1u,
                               __ATOMIC_RELEASE, __HIP_MEMORY_SCOPE_AGENT);
        const unsigned target = (unsigned)gridDim.x * (unsigned)phase;
        if (blockIdx.x == 0) {
            for (unsigned it = 0; it < (1u << 22); ++it) {
                unsigned s = 0;
#pragma unroll
                for (int i = 0; i < 16; ++i)
                    s += __hip_atomic_load(&cnt[i * 16], __ATOMIC_ACQUIRE,
                                           __HIP_MEMORY_SCOPE_AGENT);
                if (s >= target) break;
                __builtin_amdgcn_s_sleep(2);
            }
            __hip_atomic_store(rel, (unsigned)phase, __ATOMIC_RELEASE,
                               __HIP_MEMORY_SCOPE_AGENT);
        } else {
            for (unsigned it = 0; it < (1u << 22); ++it) {
                if (__hip_atomic_load(rel, __ATOMIC_ACQUIRE,
                                      __HIP_MEMORY_SCOPE_AGENT) >= (unsigned)phase)
                    break;
                __builtin_amdgcn_s_sleep(2);
            }
        }
    }
    __syncthreads();
}

// ---------------------------------------------------------------------------
// One fused kernel, 8 phases / 7 grid barriers. Grid-size-agnostic:
// every phase loops over virtual block ids with stride gridDim.x.
// ---------------------------------------------------------------------------
__global__ __launch_bounds__(256, 4) void fused(Params p) {
    __shared__ union {
        struct { float red[4][TT * DD]; float redl[4][TT]; } m;  // 36912 B
        float qred[16][16];      // phase Q
        float ins[BB][96];       // P1 staging
        float hl[HH];            // TAIL
    } u;

    const int bid = threadIdx.y + blockIdx.x;   // = blockIdx.x (ty==0)
    const int tid = threadIdx.x;
    const int grid = gridDim.x;
    unsigned* cnt = p.bar;
    unsigned* rel = p.bar + 256;

    // ---- Phase 1: q[t,e] = tt[t,:]·Wq[t,:,e] + bq  (144 virtual blocks) ---
    for (int vb = bid; vb < TT * 48; vb += grid) {
        int t = vb / 48, ec = vb % 48;
        int le = tid & 15, kg = tid >> 4;
        int e = ec * 16 + le;
        const float* w  = p.Wq + (size_t)t * DD * DD + e;
        const float* tr = p.tt + t * DD;
        float a = 0.f;
#pragma unroll 4
        for (int d = kg * 48; d < kg * 48 + 48; ++d)
            a += tr[d] * w[(size_t)d * DD];
        u.qred[kg][le] = a;
        __syncthreads();
        if (kg == 0) {
            float s = p.bq[t * DD + e];
#pragma unroll
            for (int i = 0; i < 16; ++i) s += u.qred[i][le];
            p.q[t * DD + e] = s;
        }
        __syncthreads();
    }
    gbar(cnt, rel, 1);

    // ---- Phase 2: kq[t,d] = SCALE * Wk[t,d,:]·q[t]  (576 virtual) ---------
    for (int vb = bid; vb < TT * 192; vb += grid) {
        int t = vb / 192;
        int d = (vb % 192) * 4 + (tid >> 6);
        int L = tid & 63;
        const float4* wr = (const float4*)(p.Wk + (size_t)(t * DD + d) * DD);
        const float4* qr = (const float4*)(p.q + t * DD);
        float s = 0.f;
#pragma unroll
        for (int g = 0; g < 3; ++g) {
            float4 a = wr[g * 64 + L], b = qr[g * 64 + L];
            s += a.x * b.x + a.y * b.y + a.z * b.z + a.w * b.w;
        }
#pragma unroll
        for (int off = 32; off; off >>= 1) s += __shfl_xor(s, off);
        if (L == 0) p.kq[t * DD + d] = s * SCALE;
    }
    gbar(cnt, rel, 2);

    // ---- Phase 3: MAIN stream over x (1024 fixed virtual chunks) ----------
    for (int vc = bid; vc < VC; vc += grid) {
        int b = vc >> 5, c = vc & 31;
        int w = tid >> 6, L = tid & 63;

        float* kqs = &u.m.red[0][0];
#pragma unroll
        for (int k2 = 0; k2 < 9; ++k2) kqs[tid + k2 * 256] = p.kq[tid + k2 * 256];
        __syncthreads();
        const float4* kq4 = (const float4*)kqs;

        float4 acc[TT][3] = {};
        float l[TT] = {0.f, 0.f, 0.f};
        const float* xb = p.x + (size_t)b * PP * DD;
        const int* mb = p.mask + b * PP;
        int p0 = c * ROWS + w * (ROWS / 4);

        for (int r = 0; r < ROWS / 4; ++r) {
            int pp = p0 + r;
            if (mb[pp]) continue;                  // masked rows contribute 0
            const float4* xr = (const float4*)(xb + (size_t)pp * DD);
            float4 xv[3];
#pragma unroll
            for (int g = 0; g < 3; ++g) xv[g] = xr[g * 64 + L];
            float s[TT];
#pragma unroll
            for (int t = 0; t < TT; ++t) {
                float a = 0.f;
#pragma unroll
                for (int g = 0; g < 3; ++g) {
                    float4 kf = kq4[t * 192 + g * 64 + L];
                    a += xv[g].x * kf.x + xv[g].y * kf.y
                       + xv[g].z * kf.z + xv[g].w * kf.w;
                }
                s[t] = a;
            }
#pragma unroll
            for (int off = 32; off; off >>= 1) {
                s[0] += __shfl_xor(s[0], off);
                s[1] += __shfl_xor(s[1], off);
                s[2] += __shfl_xor(s[2], off);
            }
#pragma unroll
            for (int t = 0; t < TT; ++t) {
                float e = expf(s[t]);              // scores tiny; no max needed
                l[t] += e;
#pragma unroll
                for (int g = 0; g < 3; ++g) {
                    acc[t][g].x += e * xv[g].x;
                    acc[t][g].y += e * xv[g].y;
                    acc[t][g].z += e * xv[g].z;
                    acc[t][g].w += e * xv[g].w;
                }
            }
        }

        __syncthreads();   // done reading kqs before overwrite
#pragma unroll
        for (int t = 0; t < TT; ++t)
#pragma unroll
            for (int g = 0; g < 3; ++g)
                *(float4*)&u.m.red[w][t * DD + g * 256 + 4 * L] = acc[t][g];
        if (L == 0) {
#pragma unroll
            for (int t = 0; t < TT; ++t) u.m.redl[w][t] = l[t];
        }
        __syncthreads();

        float* outp = p.xap + (size_t)vc * (TT * DD);
#pragma unroll
        for (int k = 0; k < 9; ++k) {
            int i = tid + k * 256;
            outp[i] = u.m.red[0][i] + u.m.red[1][i] + u.m.red[2][i] + u.m.red[3][i];
        }
        if (tid < TT)
            p.lp[vc * TT + tid] = u.m.redl[0][tid] + u.m.redl[1][tid]
                                + u.m.redl[2][tid] + u.m.redl[3][tid];
        __syncthreads();   // before next iteration restages kqs
    }
    gbar(cnt, rel, 3);

    // ---- Phase 4: combine chunk partials -> xa  (96 virtual) --------------
    for (int vb = bid; vb < TT * BB; vb += grid) {
        int t = vb >> 5, b = vb & 31;
        float lsum = 0.f;
#pragma unroll
        for (int c = 0; c < CC; ++c) lsum += p.lp[(b * CC + c) * TT + t];
        float inv = 1.0f / lsum;
#pragma unroll
        for (int k = 0; k < 3; ++k) {
            int d = tid + k * 256;
            float s = 0.f;
#pragma unroll
            for (int c = 0; c < CC; ++c)
                s += p.xap[(size_t)(b * CC + c) * (TT * DD) + t * DD + d];
            p.xa[(t * BB + b) * DD + d] = s * inv;
        }
    }
    gbar(cnt, rel, 4);

    // ---- Phase 5: P1V — partV[t,kc,b,e] from xa @ Wv  (288 virtual) -------
    for (int vb = bid; vb < TT * 96; vb += grid) {
        int t = vb / 96, r = vb % 96, kc = r / 12, ec = r % 12;
        for (int i = tid; i < BB * 96; i += 256) {
            int b = i / 96, kk = i % 96;
            u.ins[b][kk] = p.xa[((size_t)t * BB + b) * DD + kc * 96 + kk];
        }
        __syncthreads();
        int le = tid & 63, bg = tid >> 6;
        int e = ec * 64 + le;
        const float* wp = p.Wv + (size_t)t * DD * DD + (size_t)(kc * 96) * DD + e;
        float acc[8] = {};
#pragma unroll 4
        for (int kk = 0; kk < 96; ++kk) {
            float wv = wp[(size_t)kk * DD];
#pragma unroll
            for (int j = 0; j < 8; ++j) acc[j] += u.ins[bg * 8 + j][kk] * wv;
        }
#pragma unroll
        for (int j = 0; j < 8; ++j)
            p.partV[(((size_t)t * 8 + kc) * BB + (bg * 8 + j)) * DD + e] = acc[j];
        __syncthreads();
    }
    gbar(cnt, rel, 5);

    // ---- Phase 6: P1O — stage y = reduce(partV)+bv, times Wo  (288) -------
    for (int vb = bid; vb < TT * 96; vb += grid) {
        int t = vb / 96, r = vb % 96, kc = r / 12, ec = r % 12;
        for (int i = tid; i < BB * 96; i += 256) {
            int b = i / 96, kk = i % 96;
            int k = kc * 96 + kk;
            float s = p.bv[t * DD + k];
#pragma unroll
            for (int c8 = 0; c8 < 8; ++c8)
                s += p.partV[(((size_t)t * 8 + c8) * BB + b) * DD + k];
            u.ins[b][kk] = s;
        }
        __syncthreads();
        int le = tid & 63, bg = tid >> 6;
        int e = ec * 64 + le;
        const float* wp = p.Wo + (size_t)t * DD * DD + (size_t)(kc * 96) * DD + e;
        float acc[8] = {};
#pragma unroll 4
        for (int kk = 0; kk < 96; ++kk) {
            float wv = wp[(size_t)kk * DD];
#pragma unroll
            for (int j = 0; j < 8; ++j) acc[j] += u.ins[bg * 8 + j][kk] * wv;
        }
#pragma unroll
        for (int j = 0; j < 8; ++j)
            p.partO[(((size_t)t * 8 + kc) * BB + (bg * 8 + j)) * DD + e] = acc[j];
        __syncthreads();
    }
    gbar(cnt, rel, 6);

    // ---- Phase 7: P1H — stage y2 = reduce(partO)+bo+tt, times h1w (72) ----
    for (int vb = bid; vb < TT * 24; vb += grid) {
        int t = vb / 24, r = vb % 24, kc = r / 3, ec = r % 3;
        for (int i = tid; i < BB * 96; i += 256) {
            int b = i / 96, kk = i % 96;
            int k = kc * 96 + kk;
            float s = p.bo[t * DD + k] + p.tt[t * DD + k];
#pragma unroll
            for (int c8 = 0; c8 < 8; ++c8)
                s += p.partO[(((size_t)t * 8 + c8) * BB + b) * DD + k];
            u.ins[b][kk] = s;
        }
        __syncthreads();
        int le = tid & 63, bg = tid >> 6;
        int e = ec * 64 + le;  // 0..191
        const float* wp = p.h1w + (size_t)t * DD * HH + (size_t)(kc * 96) * HH + e;
        float acc[8] = {};
#pragma unroll 4
        for (int kk = 0; kk < 96; ++kk) {
            float wv = wp[(size_t)kk * HH];
#pragma unroll
            for (int j = 0; j < 8; ++j) acc[j] += u.ins[bg * 8 + j][kk] * wv;
        }
#pragma unroll
        for (int j = 0; j < 8; ++j)
            p.partH[(((size_t)t * 8 + kc) * BB + (bg * 8 + j)) * HH + e] = acc[j];
        __syncthreads();
    }
    gbar(cnt, rel, 7);

    // ---- Phase 8: TAIL — h = gelu(reduce(partH)+h1b); out = h@h2w+h2b -----
    for (int vb = bid; vb < TT * BB; vb += grid) {
        int t = vb / BB, b = vb % BB;
        if (tid < HH) {
            float s = p.h1b[t * HH + tid];
#pragma unroll
            for (int kc = 0; kc < 8; ++kc)
                s += p.partH[(((size_t)t * 8 + kc) * BB + b) * HH + tid];
            u.hl[tid] = 0.5f * s * (1.0f + erff(s * GELU_C));
        }
        __syncthreads();
        if (tid < OO) {
            float s = p.h2b[t * OO + tid];
#pragma unroll 8
            for (int kh = 0; kh < HH; ++kh)
                s += u.hl[kh] * p.h2w[((size_t)t * HH + kh) * OO + tid];
            p.out[((size_t)t * BB + b) * OO + tid] = s;
        }
        __syncthreads();
    }
}

// ---------------------------------------------------------------------------
extern "C" void kernel_launch(void* const* d_in, const int* in_sizes, int n_in,
                              void* d_out, int out_size, void* d_ws, size_t ws_size,
                              hipStream_t stream) {
    Params P;
    P.x    = (const float*)d_in[0];
    P.mask = (const int*)d_in[1];   // True = masked
    P.tt   = (const float*)d_in[2];
    P.Wq   = (const float*)d_in[3];
    P.bq   = (const float*)d_in[4];
    P.Wk   = (const float*)d_in[5];
    // d_in[6] = bk: cancels in softmax
    P.Wv   = (const float*)d_in[7];
    P.bv   = (const float*)d_in[8];
    P.Wo   = (const float*)d_in[9];
    P.bo   = (const float*)d_in[10];
    P.h1w  = (const float*)d_in[11];
    P.h1b  = (const float*)d_in[12];
    P.h2w  = (const float*)d_in[13];
    P.h2b  = (const float*)d_in[14];
    P.out  = (float*)d_out;

    P.bar = (unsigned*)d_ws;                    // 4 KB barrier region
    float* fws = (float*)((char*)d_ws + 4096);
    P.q     = fws;                              // 2304
    P.kq    = P.q + TT * DD;                    // 2304
    P.xap   = P.kq + TT * DD;                   // 1024*2304
    P.lp    = P.xap + (size_t)VC * TT * DD;     // 3072
    P.xa    = P.lp + VC * TT;                   // 96*768
    P.partV = P.xa + TT * BB * DD;              // 589824
    P.partO = P.partV + TT * 8 * BB * DD;       // 589824
    P.partH = P.partO + TT * 8 * BB * DD;       // 147456

    // Co-residency-safe grid from the runtime's own occupancy accounting.
    // Host-only queries: run during capture, not replay; deterministic.
    int grid = 512;                              // conservative fallback
    int dev = 0, cus = 0, perCU = 0;
    if (hipGetDevice(&dev) == hipSuccess &&
        hipDeviceGetAttribute(&cus, hipDeviceAttributeMultiprocessorCount, dev) == hipSuccess &&
        hipOccupancyMaxActiveBlocksPerMultiprocessor(&perCU, (const void*)fused, 256, 0) == hipSuccess &&
        cus > 0 && perCU > 0) {
        long g = (long)cus * (long)perCU;
        grid = (int)(g < 1024 ? g : 1024);
    }

    hipMemsetAsync(d_ws, 0, 4096, stream);      // zero barrier counters+release
    Params Pl = P;
    hipLaunchKernelGGL(fused, dim3(grid), dim3(256), 0, stream, Pl);
}

// Round 7
// 826.852 us; speedup vs baseline: 1.5493x; 1.5493x over previous
//
#include <hip/hip_runtime.h>
#include <math.h>

// Problem constants
#define BB 32
#define PP 2048
#define DD 768
#define TT 3
#define OO 128
#define HH 192
#define CC 32              // chunks of P per batch for the streaming phase
#define ROWS (PP / CC)     // 64 rows per chunk
#define VC 1024            // fixed virtual chunks for main phase (determinism)
#define ASTR 16            // arrival/release slot stride (64B lines)
#define SCALE 0.03608439182435161f  // 1/sqrt(768)
#define GELU_C 0.70710678118654752f

struct Params {
    const float* x; const int* mask; const float* tt;
    const float* Wq; const float* bq; const float* Wk;
    const float* Wv; const float* bv; const float* Wo; const float* bo;
    const float* h1w; const float* h1b; const float* h2w; const float* h2b;
    float* out;
    unsigned* arr;     // 1024 padded arrival slots (one line per block)
    unsigned* rel;     // 256 padded release lines (<=4 pollers each)
    float* q; float* kq; float* xap; float* lp; float* xa;
    float* partV; float* partO; float* partH;
};

// ---------------------------------------------------------------------------
// Grid barrier v2 — contention-free:
//  arrival: per-block own-line RELEASE store (no contention)
//  detect : block 0, 256 threads scan slots in parallel (RELAXED) +
//           __syncthreads_and; __threadfence() for the acquire edge
//  release: 256 lines, one per block-0 thread; <=4 blocks poll each line
// Bounded spins: co-residency failure -> fast wrong answer, not a hang.
// ---------------------------------------------------------------------------
__device__ inline void gbar(unsigned* arr, unsigned* rel, int phase) {
    __syncthreads();
    const int grid = gridDim.x;
    const unsigned ph = (unsigned)phase;
    if (blockIdx.x == 0) {
        if (threadIdx.x == 0)
            __hip_atomic_store(&arr[0], ph, __ATOMIC_RELEASE,
                               __HIP_MEMORY_SCOPE_AGENT);
        for (unsigned it = 0; it < (1u << 22); ++it) {
            int ok = 1;
            for (int s = threadIdx.x; s < grid; s += 256)
                ok &= (__hip_atomic_load(&arr[s * ASTR], __ATOMIC_RELAXED,
                                         __HIP_MEMORY_SCOPE_AGENT) >= ph);
            if (__syncthreads_and(ok)) break;
            __builtin_amdgcn_s_sleep(4);
        }
        __threadfence();            // order scan (acquire) before release pub
        __hip_atomic_store(&rel[threadIdx.x * ASTR], ph, __ATOMIC_RELEASE,
                           __HIP_MEMORY_SCOPE_AGENT);
        __syncthreads();
    } else {
        if (threadIdx.x == 0) {
            __hip_atomic_store(&arr[blockIdx.x * ASTR], ph, __ATOMIC_RELEASE,
                               __HIP_MEMORY_SCOPE_AGENT);
            unsigned* myrel = &rel[(blockIdx.x & 255) * ASTR];
            for (unsigned it = 0; it < (1u << 22); ++it) {
                if (__hip_atomic_load(myrel, __ATOMIC_ACQUIRE,
                                      __HIP_MEMORY_SCOPE_AGENT) >= ph)
                    break;
                __builtin_amdgcn_s_sleep(4);
            }
        }
        __syncthreads();
    }
}

// ---------------------------------------------------------------------------
// One fused kernel, 8 phases / 7 grid barriers. Grid-size-agnostic:
// every phase loops over virtual block ids with stride gridDim.x.
// ---------------------------------------------------------------------------
__global__ __launch_bounds__(256, 4) void fused(Params p) {
    __shared__ union {
        struct { float red[4][TT * DD]; float redl[4][TT]; } m;  // 36912 B
        float qred[16][16];      // phase Q
        float ins[BB][96];       // P1 staging
        float hl[HH];            // TAIL
    } u;

    const int bid = blockIdx.x;
    const int tid = threadIdx.x;
    const int grid = gridDim.x;

    // ---- Phase 1: q[t,e] = tt[t,:]·Wq[t,:,e] + bq  (144 virtual blocks) ---
    for (int vb = bid; vb < TT * 48; vb += grid) {
        int t = vb / 48, ec = vb % 48;
        int le = tid & 15, kg = tid >> 4;
        int e = ec * 16 + le;
        const float* w  = p.Wq + (size_t)t * DD * DD + e;
        const float* tr = p.tt + t * DD;
        float a = 0.f;
#pragma unroll 4
        for (int d = kg * 48; d < kg * 48 + 48; ++d)
            a += tr[d] * w[(size_t)d * DD];
        u.qred[kg][le] = a;
        __syncthreads();
        if (kg == 0) {
            float s = p.bq[t * DD + e];
#pragma unroll
            for (int i = 0; i < 16; ++i) s += u.qred[i][le];
            p.q[t * DD + e] = s;
        }
        __syncthreads();
    }
    gbar(p.arr, p.rel, 1);

    // ---- Phase 2: kq[t,d] = SCALE * Wk[t,d,:]·q[t]  (576 virtual) ---------
    for (int vb = bid; vb < TT * 192; vb += grid) {
        int t = vb / 192;
        int d = (vb % 192) * 4 + (tid >> 6);
        int L = tid & 63;
        const float4* wr = (const float4*)(p.Wk + (size_t)(t * DD + d) * DD);
        const float4* qr = (const float4*)(p.q + t * DD);
        float s = 0.f;
#pragma unroll
        for (int g = 0; g < 3; ++g) {
            float4 a = wr[g * 64 + L], b = qr[g * 64 + L];
            s += a.x * b.x + a.y * b.y + a.z * b.z + a.w * b.w;
        }
#pragma unroll
        for (int off = 32; off; off >>= 1) s += __shfl_xor(s, off);
        if (L == 0) p.kq[t * DD + d] = s * SCALE;
    }
    gbar(p.arr, p.rel, 2);

    // ---- Phase 3: MAIN stream over x (1024 fixed virtual chunks) ----------
    for (int vc = bid; vc < VC; vc += grid) {
        int b = vc >> 5, c = vc & 31;
        int w = tid >> 6, L = tid & 63;

        float* kqs = &u.m.red[0][0];
#pragma unroll
        for (int k2 = 0; k2 < 9; ++k2) kqs[tid + k2 * 256] = p.kq[tid + k2 * 256];
        __syncthreads();
        const float4* kq4 = (const float4*)kqs;

        float4 acc[TT][3] = {};
        float l[TT] = {0.f, 0.f, 0.f};
        const float* xb = p.x + (size_t)b * PP * DD;
        const int* mb = p.mask + b * PP;
        int p0 = c * ROWS + w * (ROWS / 4);

        for (int r = 0; r < ROWS / 4; ++r) {
            int pp = p0 + r;
            if (mb[pp]) continue;                  // masked rows contribute 0
            const float4* xr = (const float4*)(xb + (size_t)pp * DD);
            float4 xv[3];
#pragma unroll
            for (int g = 0; g < 3; ++g) xv[g] = xr[g * 64 + L];
            float s[TT];
#pragma unroll
            for (int t = 0; t < TT; ++t) {
                float a = 0.f;
#pragma unroll
                for (int g = 0; g < 3; ++g) {
                    float4 kf = kq4[t * 192 + g * 64 + L];
                    a += xv[g].x * kf.x + xv[g].y * kf.y
                       + xv[g].z * kf.z + xv[g].w * kf.w;
                }
                s[t] = a;
            }
#pragma unroll
            for (int off = 32; off; off >>= 1) {
                s[0] += __shfl_xor(s[0], off);
                s[1] += __shfl_xor(s[1], off);
                s[2] += __shfl_xor(s[2], off);
            }
#pragma unroll
            for (int t = 0; t < TT; ++t) {
                float e = expf(s[t]);              // scores tiny; no max needed
                l[t] += e;
#pragma unroll
                for (int g = 0; g < 3; ++g) {
                    acc[t][g].x += e * xv[g].x;
                    acc[t][g].y += e * xv[g].y;
                    acc[t][g].z += e * xv[g].z;
                    acc[t][g].w += e * xv[g].w;
                }
            }
        }

        __syncthreads();   // done reading kqs before overwrite
#pragma unroll
        for (int t = 0; t < TT; ++t)
#pragma unroll
            for (int g = 0; g < 3; ++g)
                *(float4*)&u.m.red[w][t * DD + g * 256 + 4 * L] = acc[t][g];
        if (L == 0) {
#pragma unroll
            for (int t = 0; t < TT; ++t) u.m.redl[w][t] = l[t];
        }
        __syncthreads();

        float* outp = p.xap + (size_t)vc * (TT * DD);
#pragma unroll
        for (int k = 0; k < 9; ++k) {
            int i = tid + k * 256;
            outp[i] = u.m.red[0][i] + u.m.red[1][i] + u.m.red[2][i] + u.m.red[3][i];
        }
        if (tid < TT)
            p.lp[vc * TT + tid] = u.m.redl[0][tid] + u.m.redl[1][tid]
                                + u.m.redl[2][tid] + u.m.redl[3][tid];
        __syncthreads();   // before next iteration restages kqs
    }
    gbar(p.arr, p.rel, 3);

    // ---- Phase 4: combine chunk partials -> xa  (96 virtual) --------------
    for (int vb = bid; vb < TT * BB; vb += grid) {
        int t = vb >> 5, b = vb & 31;
        float lsum = 0.f;
#pragma unroll
        for (int c = 0; c < CC; ++c) lsum += p.lp[(b * CC + c) * TT + t];
        float inv = 1.0f / lsum;
#pragma unroll
        for (int k = 0; k < 3; ++k) {
            int d = tid + k * 256;
            float s = 0.f;
#pragma unroll
            for (int c = 0; c < CC; ++c)
                s += p.xap[(size_t)(b * CC + c) * (TT * DD) + t * DD + d];
            p.xa[(t * BB + b) * DD + d] = s * inv;
        }
    }
    gbar(p.arr, p.rel, 4);

    // ---- Phase 5: P1V — partV[t,kc,b,e] from xa @ Wv  (288 virtual) -------
    for (int vb = bid; vb < TT * 96; vb += grid) {
        int t = vb / 96, r = vb % 96, kc = r / 12, ec = r % 12;
        for (int i = tid; i < BB * 96; i += 256) {
            int b = i / 96, kk = i % 96;
            u.ins[b][kk] = p.xa[((size_t)t * BB + b) * DD + kc * 96 + kk];
        }
        __syncthreads();
        int le = tid & 63, bg = tid >> 6;
        int e = ec * 64 + le;
        const float* wp = p.Wv + (size_t)t * DD * DD + (size_t)(kc * 96) * DD + e;
        float acc[8] = {};
#pragma unroll 4
        for (int kk = 0; kk < 96; ++kk) {
            float wv = wp[(size_t)kk * DD];
#pragma unroll
            for (int j = 0; j < 8; ++j) acc[j] += u.ins[bg * 8 + j][kk] * wv;
        }
#pragma unroll
        for (int j = 0; j < 8; ++j)
            p.partV[(((size_t)t * 8 + kc) * BB + (bg * 8 + j)) * DD + e] = acc[j];
        __syncthreads();
    }
    gbar(p.arr, p.rel, 5);

    // ---- Phase 6: P1O — stage y = reduce(partV)+bv, times Wo  (288) -------
    for (int vb = bid; vb < TT * 96; vb += grid) {
        int t = vb / 96, r = vb % 96, kc = r / 12, ec = r % 12;
        for (int i = tid; i < BB * 96; i += 256) {
            int b = i / 96, kk = i % 96;
            int k = kc * 96 + kk;
            float s = p.bv[t * DD + k];
#pragma unroll
            for (int c8 = 0; c8 < 8; ++c8)
                s += p.partV[(((size_t)t * 8 + c8) * BB + b) * DD + k];
            u.ins[b][kk] = s;
        }
        __syncthreads();
        int le = tid & 63, bg = tid >> 6;
        int e = ec * 64 + le;
        const float* wp = p.Wo + (size_t)t * DD * DD + (size_t)(kc * 96) * DD + e;
        float acc[8] = {};
#pragma unroll 4
        for (int kk = 0; kk < 96; ++kk) {
            float wv = wp[(size_t)kk * DD];
#pragma unroll
            for (int j = 0; j < 8; ++j) acc[j] += u.ins[bg * 8 + j][kk] * wv;
        }
#pragma unroll
        for (int j = 0; j < 8; ++j)
            p.partO[(((size_t)t * 8 + kc) * BB + (bg * 8 + j)) * DD + e] = acc[j];
        __syncthreads();
    }
    gbar(p.arr, p.rel, 6);

    // ---- Phase 7: P1H — stage y2 = reduce(partO)+bo+tt, times h1w (72) ----
    for (int vb = bid; vb < TT * 24; vb += grid) {
        int t = vb / 24, r = vb % 24, kc = r / 3, ec = r % 3;
        for (int i = tid; i < BB * 96; i += 256) {
            int b = i / 96, kk = i % 96;
            int k = kc * 96 + kk;
            float s = p.bo[t * DD + k] + p.tt[t * DD + k];
#pragma unroll
            for (int c8 = 0; c8 < 8; ++c8)
                s += p.partO[(((size_t)t * 8 + c8) * BB + b) * DD + k];
            u.ins[b][kk] = s;
        }
        __syncthreads();
        int le = tid & 63, bg = tid >> 6;
        int e = ec * 64 + le;  // 0..191
        const float* wp = p.h1w + (size_t)t * DD * HH + (size_t)(kc * 96) * HH + e;
        float acc[8] = {};
#pragma unroll 4
        for (int kk = 0; kk < 96; ++kk) {
            float wv = wp[(size_t)kk * HH];
#pragma unroll
            for (int j = 0; j < 8; ++j) acc[j] += u.ins[bg * 8 + j][kk] * wv;
        }
#pragma unroll
        for (int j = 0; j < 8; ++j)
            p.partH[(((size_t)t * 8 + kc) * BB + (bg * 8 + j)) * HH + e] = acc[j];
        __syncthreads();
    }
    gbar(p.arr, p.rel, 7);

    // ---- Phase 8: TAIL — h = gelu(reduce(partH)+h1b); out = h@h2w+h2b -----
    for (int vb = bid; vb < TT * BB; vb += grid) {
        int t = vb / BB, b = vb % BB;
        if (tid < HH) {
            float s = p.h1b[t * HH + tid];
#pragma unroll
            for (int kc = 0; kc < 8; ++kc)
                s += p.partH[(((size_t)t * 8 + kc) * BB + b) * HH + tid];
            u.hl[tid] = 0.5f * s * (1.0f + erff(s * GELU_C));
        }
        __syncthreads();
        if (tid < OO) {
            float s = p.h2b[t * OO + tid];
#pragma unroll 8
            for (int kh = 0; kh < HH; ++kh)
                s += u.hl[kh] * p.h2w[((size_t)t * HH + kh) * OO + tid];
            p.out[((size_t)t * BB + b) * OO + tid] = s;
        }
        __syncthreads();
    }
}

// ---------------------------------------------------------------------------
extern "C" void kernel_launch(void* const* d_in, const int* in_sizes, int n_in,
                              void* d_out, int out_size, void* d_ws, size_t ws_size,
                              hipStream_t stream) {
    Params P;
    P.x    = (const float*)d_in[0];
    P.mask = (const int*)d_in[1];   // True = masked
    P.tt   = (const float*)d_in[2];
    P.Wq   = (const float*)d_in[3];
    P.bq   = (const float*)d_in[4];
    P.Wk   = (const float*)d_in[5];
    // d_in[6] = bk: cancels in softmax
    P.Wv   = (const float*)d_in[7];
    P.bv   = (const float*)d_in[8];
    P.Wo   = (const float*)d_in[9];
    P.bo   = (const float*)d_in[10];
    P.h1w  = (const float*)d_in[11];
    P.h1b  = (const float*)d_in[12];
    P.h2w  = (const float*)d_in[13];
    P.h2b  = (const float*)d_in[14];
    P.out  = (float*)d_out;

    // barrier region: 1024 arrival lines (64KB) + 256 release lines (16KB)
    P.arr = (unsigned*)d_ws;
    P.rel = P.arr + 1024 * ASTR;
    float* fws = (float*)((char*)d_ws + 80 * 1024);
    P.q     = fws;                              // 2304
    P.kq    = P.q + TT * DD;                    // 2304
    P.xap   = P.kq + TT * DD;                   // 1024*2304
    P.lp    = P.xap + (size_t)VC * TT * DD;     // 3072
    P.xa    = P.lp + VC * TT;                   // 96*768
    P.partV = P.xa + TT * BB * DD;              // 589824
    P.partO = P.partV + TT * 8 * BB * DD;       // 589824
    P.partH = P.partO + TT * 8 * BB * DD;       // 147456

    // Co-residency-safe grid from the runtime's own occupancy accounting.
    int grid = 512;                              // conservative fallback
    int dev = 0, cus = 0, perCU = 0;
    if (hipGetDevice(&dev) == hipSuccess &&
        hipDeviceGetAttribute(&cus, hipDeviceAttributeMultiprocessorCount, dev) == hipSuccess &&
        hipOccupancyMaxActiveBlocksPerMultiprocessor(&perCU, (const void*)fused, 256, 0) == hipSuccess &&
        cus > 0 && perCU > 0) {
        long g = (long)cus * (long)perCU;
        grid = (int)(g < 1024 ? g : 1024);
    }

    hipMemsetAsync(d_ws, 0, 80 * 1024, stream);  // zero arrival+release lines
    Params Pl = P;
    hipLaunchKernelGGL(fused, dim3(grid), dim3(256), 0, stream, Pl);
}

// Round 8
// 151.209 us; speedup vs baseline: 8.4720x; 5.4683x over previous
//
#include <hip/hip_runtime.h>
#include <math.h>

// Problem constants
#define BB 32
#define PP 2048
#define DD 768
#define TT 3
#define OO 128
#define HH 192
#define CC 32              // chunks of P per batch for the streaming phase
#define ROWS (PP / CC)     // 64 rows per chunk
#define VC 1024            // fixed virtual chunks for main phase (determinism)
#define ASTR 16            // release slot stride (64B lines)
#define SCALE 0.03608439182435161f  // 1/sqrt(768)
#define GELU_C 0.70710678118654752f

struct Params {
    const float* x; const int* mask; const float* tt;
    const float* Wq; const float* bq; const float* Wk;
    const float* Wv; const float* bv; const float* Wo; const float* bo;
    const float* h1w; const float* h1b; const float* h2w; const float* h2b;
    float* out;
    unsigned* arr;     // 1024 packed arrival dwords (block-0 scans x4 pipelined)
    unsigned* rel;     // 256 padded release lines (<=4 pollers each)
    float* q; float* kq; float* xap; float* lp; float* xa;
    float* partV; float* partO; float* partH;
};

// L3-coherent (L2-bypassing) accessors for inter-phase intermediates.
// RELAXED agent-scope => sc-flagged load/store, NO buffer_wbl2 / buffer_inv.
__device__ inline float ld(const float* p) {
    return __hip_atomic_load(p, __ATOMIC_RELAXED, __HIP_MEMORY_SCOPE_AGENT);
}
__device__ inline void st(float* p, float v) {
    __hip_atomic_store(p, v, __ATOMIC_RELAXED, __HIP_MEMORY_SCOPE_AGENT);
}

// ---------------------------------------------------------------------------
// Grid barrier v3 — zero cache-maintenance ops.
// Entry __syncthreads() drains all waves' vmcnt (stores acked at L3, since
// all intermediate stores are sc-flagged write-through). Arrival/poll/release
// are all RELAXED agent atomics (L3-direct). Bounded spins: co-residency
// failure -> fast wrong answer, not a hang.
// ---------------------------------------------------------------------------
__device__ inline void gbar(unsigned* arr, unsigned* rel, int phase) {
    __syncthreads();   // drains vmcnt/lgkmcnt for every wave of this block
    const int grid = gridDim.x;
    const unsigned ph = (unsigned)phase;
    if (blockIdx.x == 0) {
        if (threadIdx.x == 0)
            __hip_atomic_store(&arr[0], ph, __ATOMIC_RELAXED,
                               __HIP_MEMORY_SCOPE_AGENT);
        for (unsigned it = 0; it < (1u << 22); ++it) {
            int ok = 1;
            for (int s = threadIdx.x; s < grid; s += 256)
                ok &= (__hip_atomic_load(&arr[s], __ATOMIC_RELAXED,
                                         __HIP_MEMORY_SCOPE_AGENT) >= ph);
            if (__syncthreads_and(ok)) break;
            __builtin_amdgcn_s_sleep(4);
        }
        asm volatile("" ::: "memory");
        __hip_atomic_store(&rel[threadIdx.x * ASTR], ph, __ATOMIC_RELAXED,
                           __HIP_MEMORY_SCOPE_AGENT);
        __syncthreads();
    } else {
        if (threadIdx.x == 0) {
            __hip_atomic_store(&arr[blockIdx.x], ph, __ATOMIC_RELAXED,
                               __HIP_MEMORY_SCOPE_AGENT);
            unsigned* myrel = &rel[(blockIdx.x & 255) * ASTR];
            for (unsigned it = 0; it < (1u << 22); ++it) {
                if (__hip_atomic_load(myrel, __ATOMIC_RELAXED,
                                      __HIP_MEMORY_SCOPE_AGENT) >= ph)
                    break;
                __builtin_amdgcn_s_sleep(4);
            }
            asm volatile("" ::: "memory");
        }
        __syncthreads();
    }
}

// ---------------------------------------------------------------------------
// One fused kernel, 8 phases / 7 grid barriers. Grid-size-agnostic.
// ---------------------------------------------------------------------------
__global__ __launch_bounds__(256, 4) void fused(Params p) {
    __shared__ union {
        struct { float red[4][TT * DD]; float redl[4][TT]; } m;  // 36912 B
        float qred[16][16];      // phase Q
        float ins[BB][96];       // P1 staging
        float hl[HH];            // TAIL
    } u;

    const int bid = blockIdx.x;
    const int tid = threadIdx.x;
    const int grid = gridDim.x;

    // ---- Phase 1: q[t,e] = tt[t,:]·Wq[t,:,e] + bq  (144 virtual blocks) ---
    for (int vb = bid; vb < TT * 48; vb += grid) {
        int t = vb / 48, ec = vb % 48;
        int le = tid & 15, kg = tid >> 4;
        int e = ec * 16 + le;
        const float* w  = p.Wq + (size_t)t * DD * DD + e;
        const float* tr = p.tt + t * DD;
        float a = 0.f;
#pragma unroll 4
        for (int d = kg * 48; d < kg * 48 + 48; ++d)
            a += tr[d] * w[(size_t)d * DD];
        u.qred[kg][le] = a;
        __syncthreads();
        if (kg == 0) {
            float s = p.bq[t * DD + e];
#pragma unroll
            for (int i = 0; i < 16; ++i) s += u.qred[i][le];
            st(&p.q[t * DD + e], s);
        }
        __syncthreads();
    }
    gbar(p.arr, p.rel, 1);

    // ---- Phase 2: kq[t,d] = SCALE * Wk[t,d,:]·q[t]  (576 virtual) ---------
    for (int vb = bid; vb < TT * 192; vb += grid) {
        int t = vb / 192;
        int d = (vb % 192) * 4 + (tid >> 6);
        int L = tid & 63;
        const float4* wr = (const float4*)(p.Wk + (size_t)(t * DD + d) * DD);
        const float* qb = p.q + t * DD;
        float s = 0.f;
#pragma unroll
        for (int g = 0; g < 3; ++g) {
            float4 a = wr[g * 64 + L];
            int qi = g * 256 + 4 * L;
            s += a.x * ld(&qb[qi]) + a.y * ld(&qb[qi + 1])
               + a.z * ld(&qb[qi + 2]) + a.w * ld(&qb[qi + 3]);
        }
#pragma unroll
        for (int off = 32; off; off >>= 1) s += __shfl_xor(s, off);
        if (L == 0) st(&p.kq[t * DD + d], s * SCALE);
    }
    gbar(p.arr, p.rel, 2);

    // ---- Phase 3: MAIN stream over x (1024 fixed virtual chunks) ----------
    for (int vc = bid; vc < VC; vc += grid) {
        int b = vc >> 5, c = vc & 31;
        int w = tid >> 6, L = tid & 63;

        float* kqs = &u.m.red[0][0];
#pragma unroll
        for (int k2 = 0; k2 < 9; ++k2)
            kqs[tid + k2 * 256] = ld(&p.kq[tid + k2 * 256]);
        __syncthreads();
        const float4* kq4 = (const float4*)kqs;

        float4 acc[TT][3] = {};
        float l[TT] = {0.f, 0.f, 0.f};
        const float* xb = p.x + (size_t)b * PP * DD;
        const int* mb = p.mask + b * PP;
        int p0 = c * ROWS + w * (ROWS / 4);

        for (int r = 0; r < ROWS / 4; ++r) {
            int pp = p0 + r;
            if (mb[pp]) continue;                  // masked rows contribute 0
            const float4* xr = (const float4*)(xb + (size_t)pp * DD);
            float4 xv[3];
#pragma unroll
            for (int g = 0; g < 3; ++g) xv[g] = xr[g * 64 + L];
            float s[TT];
#pragma unroll
            for (int t = 0; t < TT; ++t) {
                float a = 0.f;
#pragma unroll
                for (int g = 0; g < 3; ++g) {
                    float4 kf = kq4[t * 192 + g * 64 + L];
                    a += xv[g].x * kf.x + xv[g].y * kf.y
                       + xv[g].z * kf.z + xv[g].w * kf.w;
                }
                s[t] = a;
            }
#pragma unroll
            for (int off = 32; off; off >>= 1) {
                s[0] += __shfl_xor(s[0], off);
                s[1] += __shfl_xor(s[1], off);
                s[2] += __shfl_xor(s[2], off);
            }
#pragma unroll
            for (int t = 0; t < TT; ++t) {
                float e = expf(s[t]);              // scores tiny; no max needed
                l[t] += e;
#pragma unroll
                for (int g = 0; g < 3; ++g) {
                    acc[t][g].x += e * xv[g].x;
                    acc[t][g].y += e * xv[g].y;
                    acc[t][g].z += e * xv[g].z;
                    acc[t][g].w += e * xv[g].w;
                }
            }
        }

        __syncthreads();   // done reading kqs before overwrite
#pragma unroll
        for (int t = 0; t < TT; ++t)
#pragma unroll
            for (int g = 0; g < 3; ++g)
                *(float4*)&u.m.red[w][t * DD + g * 256 + 4 * L] = acc[t][g];
        if (L == 0) {
#pragma unroll
            for (int t = 0; t < TT; ++t) u.m.redl[w][t] = l[t];
        }
        __syncthreads();

        float* outp = p.xap + (size_t)vc * (TT * DD);
#pragma unroll
        for (int k = 0; k < 9; ++k) {
            int i = tid + k * 256;
            st(&outp[i], u.m.red[0][i] + u.m.red[1][i] + u.m.red[2][i] + u.m.red[3][i]);
        }
        if (tid < TT)
            st(&p.lp[vc * TT + tid], u.m.redl[0][tid] + u.m.redl[1][tid]
                                   + u.m.redl[2][tid] + u.m.redl[3][tid]);
        __syncthreads();   // before next iteration restages kqs
    }
    gbar(p.arr, p.rel, 3);

    // ---- Phase 4: combine chunk partials -> xa  (96 virtual) --------------
    for (int vb = bid; vb < TT * BB; vb += grid) {
        int t = vb >> 5, b = vb & 31;
        float lsum = 0.f;
#pragma unroll
        for (int c = 0; c < CC; ++c) lsum += ld(&p.lp[(b * CC + c) * TT + t]);
        float inv = 1.0f / lsum;
#pragma unroll
        for (int k = 0; k < 3; ++k) {
            int d = tid + k * 256;
            float s = 0.f;
#pragma unroll
            for (int c = 0; c < CC; ++c)
                s += ld(&p.xap[(size_t)(b * CC + c) * (TT * DD) + t * DD + d]);
            st(&p.xa[(t * BB + b) * DD + d], s * inv);
        }
    }
    gbar(p.arr, p.rel, 4);

    // ---- Phase 5: P1V — partV[t,kc,b,e] from xa @ Wv  (288 virtual) -------
    for (int vb = bid; vb < TT * 96; vb += grid) {
        int t = vb / 96, r = vb % 96, kc = r / 12, ec = r % 12;
        for (int i = tid; i < BB * 96; i += 256) {
            int b = i / 96, kk = i % 96;
            u.ins[b][kk] = ld(&p.xa[((size_t)t * BB + b) * DD + kc * 96 + kk]);
        }
        __syncthreads();
        int le = tid & 63, bg = tid >> 6;
        int e = ec * 64 + le;
        const float* wp = p.Wv + (size_t)t * DD * DD + (size_t)(kc * 96) * DD + e;
        float acc[8] = {};
#pragma unroll 4
        for (int kk = 0; kk < 96; ++kk) {
            float wv = wp[(size_t)kk * DD];
#pragma unroll
            for (int j = 0; j < 8; ++j) acc[j] += u.ins[bg * 8 + j][kk] * wv;
        }
#pragma unroll
        for (int j = 0; j < 8; ++j)
            st(&p.partV[(((size_t)t * 8 + kc) * BB + (bg * 8 + j)) * DD + e], acc[j]);
        __syncthreads();
    }
    gbar(p.arr, p.rel, 5);

    // ---- Phase 6: P1O — stage y = reduce(partV)+bv, times Wo  (288) -------
    for (int vb = bid; vb < TT * 96; vb += grid) {
        int t = vb / 96, r = vb % 96, kc = r / 12, ec = r % 12;
        for (int i = tid; i < BB * 96; i += 256) {
            int b = i / 96, kk = i % 96;
            int k = kc * 96 + kk;
            float s = p.bv[t * DD + k];
#pragma unroll
            for (int c8 = 0; c8 < 8; ++c8)
                s += ld(&p.partV[(((size_t)t * 8 + c8) * BB + b) * DD + k]);
            u.ins[b][kk] = s;
        }
        __syncthreads();
        int le = tid & 63, bg = tid >> 6;
        int e = ec * 64 + le;
        const float* wp = p.Wo + (size_t)t * DD * DD + (size_t)(kc * 96) * DD + e;
        float acc[8] = {};
#pragma unroll 4
        for (int kk = 0; kk < 96; ++kk) {
            float wv = wp[(size_t)kk * DD];
#pragma unroll
            for (int j = 0; j < 8; ++j) acc[j] += u.ins[bg * 8 + j][kk] * wv;
        }
#pragma unroll
        for (int j = 0; j < 8; ++j)
            st(&p.partO[(((size_t)t * 8 + kc) * BB + (bg * 8 + j)) * DD + e], acc[j]);
        __syncthreads();
    }
    gbar(p.arr, p.rel, 6);

    // ---- Phase 7: P1H — stage y2 = reduce(partO)+bo+tt, times h1w (72) ----
    for (int vb = bid; vb < TT * 24; vb += grid) {
        int t = vb / 24, r = vb % 24, kc = r / 3, ec = r % 3;
        for (int i = tid; i < BB * 96; i += 256) {
            int b = i / 96, kk = i % 96;
            int k = kc * 96 + kk;
            float s = p.bo[t * DD + k] + p.tt[t * DD + k];
#pragma unroll
            for (int c8 = 0; c8 < 8; ++c8)
                s += ld(&p.partO[(((size_t)t * 8 + c8) * BB + b) * DD + k]);
            u.ins[b][kk] = s;
        }
        __syncthreads();
        int le = tid & 63, bg = tid >> 6;
        int e = ec * 64 + le;  // 0..191
        const float* wp = p.h1w + (size_t)t * DD * HH + (size_t)(kc * 96) * HH + e;
        float acc[8] = {};
#pragma unroll 4
        for (int kk = 0; kk < 96; ++kk) {
            float wv = wp[(size_t)kk * HH];
#pragma unroll
            for (int j = 0; j < 8; ++j) acc[j] += u.ins[bg * 8 + j][kk] * wv;
        }
#pragma unroll
        for (int j = 0; j < 8; ++j)
            st(&p.partH[(((size_t)t * 8 + kc) * BB + (bg * 8 + j)) * HH + e], acc[j]);
        __syncthreads();
    }
    gbar(p.arr, p.rel, 7);

    // ---- Phase 8: TAIL — h = gelu(reduce(partH)+h1b); out = h@h2w+h2b -----
    for (int vb = bid; vb < TT * BB; vb += grid) {
        int t = vb / BB, b = vb % BB;
        if (tid < HH) {
            float s = p.h1b[t * HH + tid];
#pragma unroll
            for (int kc = 0; kc < 8; ++kc)
                s += ld(&p.partH[(((size_t)t * 8 + kc) * BB + b) * HH + tid]);
            u.hl[tid] = 0.5f * s * (1.0f + erff(s * GELU_C));
        }
        __syncthreads();
        if (tid < OO) {
            float s = p.h2b[t * OO + tid];
#pragma unroll 8
            for (int kh = 0; kh < HH; ++kh)
                s += u.hl[kh] * p.h2w[((size_t)t * HH + kh) * OO + tid];
            p.out[((size_t)t * BB + b) * OO + tid] = s;
        }
        __syncthreads();
    }
}

// ---------------------------------------------------------------------------
extern "C" void kernel_launch(void* const* d_in, const int* in_sizes, int n_in,
                              void* d_out, int out_size, void* d_ws, size_t ws_size,
                              hipStream_t stream) {
    Params P;
    P.x    = (const float*)d_in[0];
    P.mask = (const int*)d_in[1];   // True = masked
    P.tt   = (const float*)d_in[2];
    P.Wq   = (const float*)d_in[3];
    P.bq   = (const float*)d_in[4];
    P.Wk   = (const float*)d_in[5];
    // d_in[6] = bk: cancels in softmax
    P.Wv   = (const float*)d_in[7];
    P.bv   = (const float*)d_in[8];
    P.Wo   = (const float*)d_in[9];
    P.bo   = (const float*)d_in[10];
    P.h1w  = (const float*)d_in[11];
    P.h1b  = (const float*)d_in[12];
    P.h2w  = (const float*)d_in[13];
    P.h2b  = (const float*)d_in[14];
    P.out  = (float*)d_out;

    // barrier region: 1024 packed arrival dwords (4KB) + 256 release lines (16KB)
    P.arr = (unsigned*)d_ws;
    P.rel = P.arr + 1024;
    float* fws = (float*)((char*)d_ws + 32 * 1024);
    P.q     = fws;                              // 2304
    P.kq    = P.q + TT * DD;                    // 2304
    P.xap   = P.kq + TT * DD;                   // 1024*2304
    P.lp    = P.xap + (size_t)VC * TT * DD;     // 3072
    P.xa    = P.lp + VC * TT;                   // 96*768
    P.partV = P.xa + TT * BB * DD;              // 589824
    P.partO = P.partV + TT * 8 * BB * DD;       // 589824
    P.partH = P.partO + TT * 8 * BB * DD;       // 147456

    // Co-residency-safe grid from the runtime's own occupancy accounting.
    int grid = 512;                              // conservative fallback
    int dev = 0, cus = 0, perCU = 0;
    if (hipGetDevice(&dev) == hipSuccess &&
        hipDeviceGetAttribute(&cus, hipDeviceAttributeMultiprocessorCount, dev) == hipSuccess &&
        hipOccupancyMaxActiveBlocksPerMultiprocessor(&perCU, (const void*)fused, 256, 0) == hipSuccess &&
        cus > 0 && perCU > 0) {
        long g = (long)cus * (long)perCU;
        grid = (int)(g < 1024 ? g : 1024);
    }

    hipMemsetAsync(d_ws, 0, 32 * 1024, stream);  // zero arrival+release words
    Params Pl = P;
    hipLaunchKernelGGL(fused, dim3(grid), dim3(256), 0, stream, Pl);
}

// Round 9
// 147.540 us; speedup vs baseline: 8.6827x; 1.0249x over previous
//
#include <hip/hip_runtime.h>
#include <math.h>

// Problem constants
#define BB 32
#define PP 2048
#define DD 768
#define TT 3
#define OO 128
#define HH 192
#define CC 32              // chunks of P per batch for the streaming phase
#define ROWS (PP / CC)     // 64 rows per chunk
#define VC 1024            // fixed virtual chunks for main phase (determinism)
#define ASTR 16            // release slot stride (64B lines)
#define SCALE 0.03608439182435161f  // 1/sqrt(768)
#define GELU_C 0.70710678118654752f

struct Params {
    const float* x; const int* mask; const float* tt;
    const float* Wq; const float* bq; const float* Wk;
    const float* Wv; const float* bv; const float* Wo; const float* bo;
    const float* h1w; const float* h1b; const float* h2w; const float* h2b;
    float* out;
    unsigned* arr;     // 1024 packed arrival dwords
    unsigned* rel;     // 256 padded release lines (<=4 pollers each)
    float* q; float* kq; float* xap; float* lp; float* xa;
    float* partV; float* partO; float* partH;
};

// L3-coherent (L2-bypassing) accessors for inter-phase intermediates.
// RELAXED agent-scope => sc-flagged load/store, NO buffer_wbl2 / buffer_inv.
__device__ inline float ld(const float* p) {
    return __hip_atomic_load(p, __ATOMIC_RELAXED, __HIP_MEMORY_SCOPE_AGENT);
}
__device__ inline void st(float* p, float v) {
    __hip_atomic_store(p, v, __ATOMIC_RELAXED, __HIP_MEMORY_SCOPE_AGENT);
}

// ---------------------------------------------------------------------------
// Grid barrier v3 (round-8 verified) — zero cache-maintenance ops.
// ---------------------------------------------------------------------------
__device__ inline void gbar(unsigned* arr, unsigned* rel, int phase) {
    __syncthreads();   // drains vmcnt/lgkmcnt for every wave of this block
    const int grid = gridDim.x;
    const unsigned ph = (unsigned)phase;
    if (blockIdx.x == 0) {
        if (threadIdx.x == 0)
            __hip_atomic_store(&arr[0], ph, __ATOMIC_RELAXED,
                               __HIP_MEMORY_SCOPE_AGENT);
        for (unsigned it = 0; it < (1u << 22); ++it) {
            int ok = 1;
            for (int s = threadIdx.x; s < grid; s += 256)
                ok &= (__hip_atomic_load(&arr[s], __ATOMIC_RELAXED,
                                         __HIP_MEMORY_SCOPE_AGENT) >= ph);
            if (__syncthreads_and(ok)) break;
            __builtin_amdgcn_s_sleep(1);
        }
        asm volatile("" ::: "memory");
        __hip_atomic_store(&rel[threadIdx.x * ASTR], ph, __ATOMIC_RELAXED,
                           __HIP_MEMORY_SCOPE_AGENT);
        __syncthreads();
    } else {
        if (threadIdx.x == 0) {
            __hip_atomic_store(&arr[blockIdx.x], ph, __ATOMIC_RELAXED,
                               __HIP_MEMORY_SCOPE_AGENT);
            unsigned* myrel = &rel[(blockIdx.x & 255) * ASTR];
            for (unsigned it = 0; it < (1u << 22); ++it) {
                if (__hip_atomic_load(myrel, __ATOMIC_RELAXED,
                                      __HIP_MEMORY_SCOPE_AGENT) >= ph)
                    break;
                __builtin_amdgcn_s_sleep(1);
            }
            asm volatile("" ::: "memory");
        }
        __syncthreads();
    }
}

// ---------------------------------------------------------------------------
// One fused kernel, 8 phases / 7 grid barriers. Grid-size-agnostic.
// ---------------------------------------------------------------------------
__global__ __launch_bounds__(256, 4) void fused(Params p) {
    __shared__ union {
        struct { float red[4][TT * DD]; float redl[4][TT]; } m;  // 36912 B
        float qred[16][16];      // phase Q
        float ins[BB][96];       // P1 staging
        float hl[HH];            // TAIL
    } u;

    const int bid = blockIdx.x;
    const int tid = threadIdx.x;
    const int grid = gridDim.x;

    // ---- Phase 1: q[t,e] = tt[t,:]·Wq[t,:,e] + bq  (144 virtual blocks) ---
    for (int vb = bid; vb < TT * 48; vb += grid) {
        int t = vb / 48, ec = vb % 48;
        int le = tid & 15, kg = tid >> 4;
        int e = ec * 16 + le;
        const float* w  = p.Wq + (size_t)t * DD * DD + e;
        const float* tr = p.tt + t * DD;
        float a = 0.f;
#pragma unroll 4
        for (int d = kg * 48; d < kg * 48 + 48; ++d)
            a += tr[d] * w[(size_t)d * DD];
        u.qred[kg][le] = a;
        __syncthreads();
        if (kg == 0) {
            float s = p.bq[t * DD + e];
#pragma unroll
            for (int i = 0; i < 16; ++i) s += u.qred[i][le];
            st(&p.q[t * DD + e], s);
        }
        __syncthreads();
    }
    gbar(p.arr, p.rel, 1);

    // ---- Phase 2: kq[t,d] = SCALE * Wk[t,d,:]·q[t]  (576 virtual) ---------
    for (int vb = bid; vb < TT * 192; vb += grid) {
        int t = vb / 192;
        int d = (vb % 192) * 4 + (tid >> 6);
        int L = tid & 63;
        const float4* wr = (const float4*)(p.Wk + (size_t)(t * DD + d) * DD);
        const float* qb = p.q + t * DD;
        float s = 0.f;
#pragma unroll
        for (int g = 0; g < 3; ++g) {
            float4 a = wr[g * 64 + L];
            int qi = g * 256 + 4 * L;
            s += a.x * ld(&qb[qi]) + a.y * ld(&qb[qi + 1])
               + a.z * ld(&qb[qi + 2]) + a.w * ld(&qb[qi + 3]);
        }
#pragma unroll
        for (int off = 32; off; off >>= 1) s += __shfl_xor(s, off);
        if (L == 0) st(&p.kq[t * DD + d], s * SCALE);
    }
    gbar(p.arr, p.rel, 2);

    // ---- Phase 3: MAIN stream over x (1024 fixed virtual chunks) ----------
    {
        const int w = tid >> 6, L = tid & 63;
        // kq in REGISTERS (was LDS: 288 ds_read_b128/thread, 8-way conflicts)
        float4 kqr[TT][3];
#pragma unroll
        for (int t = 0; t < TT; ++t)
#pragma unroll
            for (int g = 0; g < 3; ++g) {
                int base = t * DD + g * 256 + 4 * L;
                kqr[t][g].x = ld(&p.kq[base]);
                kqr[t][g].y = ld(&p.kq[base + 1]);
                kqr[t][g].z = ld(&p.kq[base + 2]);
                kqr[t][g].w = ld(&p.kq[base + 3]);
            }

        for (int vc = bid; vc < VC; vc += grid) {
            int b = vc >> 5, c = vc & 31;

            float4 acc[TT][3] = {};
            float l[TT] = {0.f, 0.f, 0.f};
            const float* xb = p.x + (size_t)b * PP * DD;
            const int* mb = p.mask + b * PP;
            int p0 = c * ROWS + w * 16;

            // prefetch 16 masks -> bitmask (kills per-row dependent mask load)
            const int4* m4 = (const int4*)&mb[p0];
            int4 ma = m4[0], mbv = m4[1], mc = m4[2], md = m4[3];
            unsigned bits = 0;
            bits |= (ma.x  != 0) << 0;  bits |= (ma.y  != 0) << 1;
            bits |= (ma.z  != 0) << 2;  bits |= (ma.w  != 0) << 3;
            bits |= (mbv.x != 0) << 4;  bits |= (mbv.y != 0) << 5;
            bits |= (mbv.z != 0) << 6;  bits |= (mbv.w != 0) << 7;
            bits |= (mc.x  != 0) << 8;  bits |= (mc.y  != 0) << 9;
            bits |= (mc.z  != 0) << 10; bits |= (mc.w  != 0) << 11;
            bits |= (md.x  != 0) << 12; bits |= (md.y  != 0) << 13;
            bits |= (md.z  != 0) << 14; bits |= (md.w  != 0) << 15;

#pragma unroll 4
            for (int r = 0; r < 16; ++r) {
                if (bits & (1u << r)) continue;    // masked rows contribute 0
                const float4* xr = (const float4*)(xb + (size_t)(p0 + r) * DD);
                float4 xv[3];
#pragma unroll
                for (int g = 0; g < 3; ++g) xv[g] = xr[g * 64 + L];
                float s[TT];
#pragma unroll
                for (int t = 0; t < TT; ++t) {
                    float a = 0.f;
#pragma unroll
                    for (int g = 0; g < 3; ++g)
                        a += xv[g].x * kqr[t][g].x + xv[g].y * kqr[t][g].y
                           + xv[g].z * kqr[t][g].z + xv[g].w * kqr[t][g].w;
                    s[t] = a;
                }
#pragma unroll
                for (int off = 32; off; off >>= 1) {
                    s[0] += __shfl_xor(s[0], off);
                    s[1] += __shfl_xor(s[1], off);
                    s[2] += __shfl_xor(s[2], off);
                }
#pragma unroll
                for (int t = 0; t < TT; ++t) {
                    float e = __expf(s[t]);        // scores tiny; no max needed
                    l[t] += e;
#pragma unroll
                    for (int g = 0; g < 3; ++g) {
                        acc[t][g].x += e * xv[g].x;
                        acc[t][g].y += e * xv[g].y;
                        acc[t][g].z += e * xv[g].z;
                        acc[t][g].w += e * xv[g].w;
                    }
                }
            }

            __syncthreads();   // red[] free (prev iteration fully consumed)
#pragma unroll
            for (int t = 0; t < TT; ++t)
#pragma unroll
                for (int g = 0; g < 3; ++g)
                    *(float4*)&u.m.red[w][t * DD + g * 256 + 4 * L] = acc[t][g];
            if (L == 0) {
#pragma unroll
                for (int t = 0; t < TT; ++t) u.m.redl[w][t] = l[t];
            }
            __syncthreads();

            float* outp = p.xap + (size_t)vc * (TT * DD);
#pragma unroll
            for (int k = 0; k < 9; ++k) {
                int i = tid + k * 256;
                st(&outp[i], u.m.red[0][i] + u.m.red[1][i]
                           + u.m.red[2][i] + u.m.red[3][i]);
            }
            if (tid < TT)
                st(&p.lp[vc * TT + tid], u.m.redl[0][tid] + u.m.redl[1][tid]
                                       + u.m.redl[2][tid] + u.m.redl[3][tid]);
        }
    }
    gbar(p.arr, p.rel, 3);

    // ---- Phase 4: combine chunk partials -> xa  (96 virtual) --------------
    for (int vb = bid; vb < TT * BB; vb += grid) {
        int t = vb >> 5, b = vb & 31;
        float lsum = 0.f;
#pragma unroll
        for (int c = 0; c < CC; ++c) lsum += ld(&p.lp[(b * CC + c) * TT + t]);
        float inv = 1.0f / lsum;
#pragma unroll
        for (int k = 0; k < 3; ++k) {
            int d = tid + k * 256;
            float s = 0.f;
#pragma unroll
            for (int c = 0; c < CC; ++c)
                s += ld(&p.xap[(size_t)(b * CC + c) * (TT * DD) + t * DD + d]);
            st(&p.xa[(t * BB + b) * DD + d], s * inv);
        }
    }
    gbar(p.arr, p.rel, 4);

    // ---- Phase 5: P1V — partV[t,kc,b,e] from xa @ Wv  (288 virtual) -------
    for (int vb = bid; vb < TT * 96; vb += grid) {
        int t = vb / 96, r = vb % 96, kc = r / 12, ec = r % 12;
        for (int i = tid; i < BB * 96; i += 256) {
            int b = i / 96, kk = i % 96;
            u.ins[b][kk] = ld(&p.xa[((size_t)t * BB + b) * DD + kc * 96 + kk]);
        }
        __syncthreads();
        int le = tid & 63, bg = tid >> 6;
        int e = ec * 64 + le;
        const float* wp = p.Wv + (size_t)t * DD * DD + (size_t)(kc * 96) * DD + e;
        float acc[8] = {};
#pragma unroll 4
        for (int kk = 0; kk < 96; ++kk) {
            float wv = wp[(size_t)kk * DD];
#pragma unroll
            for (int j = 0; j < 8; ++j) acc[j] += u.ins[bg * 8 + j][kk] * wv;
        }
#pragma unroll
        for (int j = 0; j < 8; ++j)
            st(&p.partV[(((size_t)t * 8 + kc) * BB + (bg * 8 + j)) * DD + e], acc[j]);
        __syncthreads();
    }
    gbar(p.arr, p.rel, 5);

    // ---- Phase 6: P1O — stage y = reduce(partV)+bv, times Wo  (288) -------
    for (int vb = bid; vb < TT * 96; vb += grid) {
        int t = vb / 96, r = vb % 96, kc = r / 12, ec = r % 12;
        for (int i = tid; i < BB * 96; i += 256) {
            int b = i / 96, kk = i % 96;
            int k = kc * 96 + kk;
            float s = p.bv[t * DD + k];
#pragma unroll
            for (int c8 = 0; c8 < 8; ++c8)
                s += ld(&p.partV[(((size_t)t * 8 + c8) * BB + b) * DD + k]);
            u.ins[b][kk] = s;
        }
        __syncthreads();
        int le = tid & 63, bg = tid >> 6;
        int e = ec * 64 + le;
        const float* wp = p.Wo + (size_t)t * DD * DD + (size_t)(kc * 96) * DD + e;
        float acc[8] = {};
#pragma unroll 4
        for (int kk = 0; kk < 96; ++kk) {
            float wv = wp[(size_t)kk * DD];
#pragma unroll
            for (int j = 0; j < 8; ++j) acc[j] += u.ins[bg * 8 + j][kk] * wv;
        }
#pragma unroll
        for (int j = 0; j < 8; ++j)
            st(&p.partO[(((size_t)t * 8 + kc) * BB + (bg * 8 + j)) * DD + e], acc[j]);
        __syncthreads();
    }
    gbar(p.arr, p.rel, 6);

    // ---- Phase 7: P1H — stage y2 = reduce(partO)+bo+tt, times h1w (72) ----
    for (int vb = bid; vb < TT * 24; vb += grid) {
        int t = vb / 24, r = vb % 24, kc = r / 3, ec = r % 3;
        for (int i = tid; i < BB * 96; i += 256) {
            int b = i / 96, kk = i % 96;
            int k = kc * 96 + kk;
            float s = p.bo[t * DD + k] + p.tt[t * DD + k];
#pragma unroll
            for (int c8 = 0; c8 < 8; ++c8)
                s += ld(&p.partO[(((size_t)t * 8 + c8) * BB + b) * DD + k]);
            u.ins[b][kk] = s;
        }
        __syncthreads();
        int le = tid & 63, bg = tid >> 6;
        int e = ec * 64 + le;  // 0..191
        const float* wp = p.h1w + (size_t)t * DD * HH + (size_t)(kc * 96) * HH + e;
        float acc[8] = {};
#pragma unroll 4
        for (int kk = 0; kk < 96; ++kk) {
            float wv = wp[(size_t)kk * HH];
#pragma unroll
            for (int j = 0; j < 8; ++j) acc[j] += u.ins[bg * 8 + j][kk] * wv;
        }
#pragma unroll
        for (int j = 0; j < 8; ++j)
            st(&p.partH[(((size_t)t * 8 + kc) * BB + (bg * 8 + j)) * HH + e], acc[j]);
        __syncthreads();
    }
    gbar(p.arr, p.rel, 7);

    // ---- Phase 8: TAIL — h = gelu(reduce(partH)+h1b); out = h@h2w+h2b -----
    for (int vb = bid; vb < TT * BB; vb += grid) {
        int t = vb / BB, b = vb % BB;
        if (tid < HH) {
            float s = p.h1b[t * HH + tid];
#pragma unroll
            for (int kc = 0; kc < 8; ++kc)
                s += ld(&p.partH[(((size_t)t * 8 + kc) * BB + b) * HH + tid]);
            u.hl[tid] = 0.5f * s * (1.0f + erff(s * GELU_C));
        }
        __syncthreads();
        if (tid < OO) {
            float s = p.h2b[t * OO + tid];
#pragma unroll 8
            for (int kh = 0; kh < HH; ++kh)
                s += u.hl[kh] * p.h2w[((size_t)t * HH + kh) * OO + tid];
            p.out[((size_t)t * BB + b) * OO + tid] = s;
        }
        __syncthreads();
    }
}

// ---------------------------------------------------------------------------
extern "C" void kernel_launch(void* const* d_in, const int* in_sizes, int n_in,
                              void* d_out, int out_size, void* d_ws, size_t ws_size,
                              hipStream_t stream) {
    Params P;
    P.x    = (const float*)d_in[0];
    P.mask = (const int*)d_in[1];   // True = masked
    P.tt   = (const float*)d_in[2];
    P.Wq   = (const float*)d_in[3];
    P.bq   = (const float*)d_in[4];
    P.Wk   = (const float*)d_in[5];
    // d_in[6] = bk: cancels in softmax
    P.Wv   = (const float*)d_in[7];
    P.bv   = (const float*)d_in[8];
    P.Wo   = (const float*)d_in[9];
    P.bo   = (const float*)d_in[10];
    P.h1w  = (const float*)d_in[11];
    P.h1b  = (const float*)d_in[12];
    P.h2w  = (const float*)d_in[13];
    P.h2b  = (const float*)d_in[14];
    P.out  = (float*)d_out;

    // barrier region: 1024 packed arrival dwords (4KB) + 256 release lines (16KB)
    P.arr = (unsigned*)d_ws;
    P.rel = P.arr + 1024;
    float* fws = (float*)((char*)d_ws + 32 * 1024);
    P.q     = fws;                              // 2304
    P.kq    = P.q + TT * DD;                    // 2304
    P.xap   = P.kq + TT * DD;                   // 1024*2304
    P.lp    = P.xap + (size_t)VC * TT * DD;     // 3072
    P.xa    = P.lp + VC * TT;                   // 96*768
    P.partV = P.xa + TT * BB * DD;              // 589824
    P.partO = P.partV + TT * 8 * BB * DD;       // 589824
    P.partH = P.partO + TT * 8 * BB * DD;       // 147456

    // Co-residency-safe grid from the runtime's own occupancy accounting.
    int grid = 512;                              // conservative fallback
    int dev = 0, cus = 0, perCU = 0;
    if (hipGetDevice(&dev) == hipSuccess &&
        hipDeviceGetAttribute(&cus, hipDeviceAttributeMultiprocessorCount, dev) == hipSuccess &&
        hipOccupancyMaxActiveBlocksPerMultiprocessor(&perCU, (const void*)fused, 256, 0) == hipSuccess &&
        cus > 0 && perCU > 0) {
        long g = (long)cus * (long)perCU;
        grid = (int)(g < 1024 ? g : 1024);
    }

    hipMemsetAsync(d_ws, 0, 32 * 1024, stream);  // zero arrival+release words
    Params Pl = P;
    hipLaunchKernelGGL(fused, dim3(grid), dim3(256), 0, stream, Pl);
}